// Round 9
// baseline (27.712 us; speedup 1.0000x reference)
//
#include <hip/hip_runtime.h>

// YOLO loss, MI355X.
// R9 = R8 dense/target math + single-kernel fusion via PER-BLOCK FLAGS:
//   2016 producer blocks publish partials (relaxed agent-scope 8B atomic
//   stores, R6-proven cheap+visible), s_waitcnt vmcnt(0), then set their OWN
//   flag (distinct address, plain atomic store - NO RMW). One finalizer
//   block polls the flag array and reduces. Flags zeroed per launch by an
//   8KB memset node.
// R4/R6 lesson (permanent): NO same-address cross-block atomics on gfx950 —
// ordered RMW => per-XCD L2 wb/inv (~100us); relaxed RMW => ~25ns x N
// serialization at the coherence point (~50us for 2016).

#define NB 32      // batch
#define NT 60      // targets per image
#define NC 20      // classes
#define THREADS 256

#define TGTB 96               // 3 scales * 32 batches, blocks 0..95
// dense: 96 groups/scale; blocks-per-group {15,4,1}; mixed first, then pure
#define DM  288               // mixed blocks: 96 per scale
#define DP0 1344              // scale0 pure: 96*14
#define DP1 288               // scale1 pure: 96*3
#define DENSB (DM + DP0 + DP1)   // 1920
#define PRODB (TGTB + DENSB)     // 2016 producers
#define PB0 2240              // f4/block scale0 (8*256 + 192)
#define PB12 2100             // f4/block scale1/2 (8*256 + 52)

// ws float layout: [0..383] tgt partials 96*4; [384..4223] dense 1920*2;
// flags: uint[2016] at float index 4224 (byte 16896), memset each launch.
#define WS_DENSE 384
#define WS_FLAGS 4224

#define SCOPE_AGENT __HIP_MEMORY_SCOPE_AGENT

__constant__ float c_anch[3][3][2] = {
  {{10.f/640.f, 13.f/640.f}, {16.f/640.f, 30.f/640.f}, {33.f/640.f, 23.f/640.f}},
  {{30.f/640.f, 61.f/640.f}, {62.f/640.f, 45.f/640.f}, {59.f/640.f, 119.f/640.f}},
  {{116.f/640.f, 90.f/640.f}, {156.f/640.f, 198.f/640.f}, {373.f/640.f, 326.f/640.f}},
};

__device__ __forceinline__ float sigm(float x) {
  return 1.f / (1.f + __expf(-x));
}
// one factor of the softplus product: 1 + exp(-|x|)
__device__ __forceinline__ float spf(float x) {
  return 1.f + __expf(-fabsf(x));
}
__device__ __forceinline__ float relu4(float4 v) {
  return (fmaxf(v.x, 0.f) + fmaxf(v.y, 0.f)) + (fmaxf(v.z, 0.f) + fmaxf(v.w, 0.f));
}
__device__ __forceinline__ float prod4(float4 v) {
  return (spf(v.x) * spf(v.y)) * (spf(v.z) * spf(v.w));
}
// relaxed agent-scope 8B publish/read (R6-proven: cheap + cross-XCD visible)
__device__ __forceinline__ void store2_rlx(float* p, float a, float b) {
  union { float f[2]; unsigned long long u; } pk;
  pk.f[0] = a; pk.f[1] = b;
  __hip_atomic_store((unsigned long long*)p, pk.u, __ATOMIC_RELAXED, SCOPE_AGENT);
}
__device__ __forceinline__ float2 load2_rlx(const float* p) {
  union { unsigned long long u; float f[2]; } pk;
  pk.u = __hip_atomic_load((const unsigned long long*)p, __ATOMIC_RELAXED, SCOPE_AGENT);
  return make_float2(pk.f[0], pk.f[1]);
}

// ---- dense block (R8): MIXED = sub==0 (has the obj plane); else pure-cls.
template<int HW, bool MIXED, int PB>
__device__ void sum_dense(const float* __restrict__ bp, int sub,
                          float* __restrict__ outp) {
  const int OBJ4 = HW / 4;
  const int FULLOBJ = OBJ4 >> 8;    // rounds fully inside obj: 6 / 1 / 0
  const int BLIM = OBJ4 & 255;      // boundary-round lane limit: 64/144/100
  int tid = threadIdx.x;
  int k0 = (MIXED ? 0 : sub * PB) + tid;
  float4 v[8];
#pragma unroll
  for (int u = 0; u < 8; ++u)
    v[u] = *reinterpret_cast<const float4*>(bp + 4 * (k0 + u * 256));
  const int TAIL = PB - 2048;                  // 192 or 52
  bool hasTail = tid < TAIL;
  float4 vt = make_float4(0.f, 0.f, 0.f, 0.f);
  if (hasTail) vt = *reinterpret_cast<const float4*>(bp + 4 * (k0 + 2048));

  float reluO = 0.f, prodO = 1.f;
  float reluC = 0.f, prodC = 1.f;
#pragma unroll
  for (int u = 0; u < 8; ++u) {
    float r = relu4(v[u]);
    float pr = prod4(v[u]);
    if (MIXED && u < FULLOBJ) {            // compile-time: all obj
      reluO += r; prodO *= pr;
    } else if (MIXED && u == FULLOBJ) {    // the ONE per-lane round
      bool isO = tid < BLIM;
      reluO += isO ? r : 0.f;
      reluC += isO ? 0.f : r;
      prodO *= isO ? pr : 1.f;
      prodC *= isO ? 1.f : pr;
    } else {                                // compile-time: all cls
      reluC += r; prodC *= pr;
    }
  }
  {                                         // tail is always cls
    reluC += relu4(vt);
    prodC *= hasTail ? prod4(vt) : 1.f;
  }
  float accO = MIXED ? (reluO + __logf(prodO)) : 0.f;
  float accC = reluC + __logf(prodC);
#pragma unroll
  for (int o = 32; o > 0; o >>= 1) {
    if (MIXED) accO += __shfl_down(accO, o, 64);
    accC += __shfl_down(accC, o, 64);
  }
  __shared__ float sO[4], sC[4];
  int wid = threadIdx.x >> 6, lane = threadIdx.x & 63;
  if (lane == 0) { sO[wid] = accO; sC[wid] = accC; }
  __syncthreads();
  if (threadIdx.x == 0)
    store2_rlx(outp, MIXED ? (sO[0] + sO[1] + sO[2] + sO[3]) : 0.f,
                     sC[0] + sC[1] + sC[2] + sC[3]);
}

// ---- sparse target part: one block per (scale, n) ----
__device__ void target_block(const float* __restrict__ pred,
                             const float* __restrict__ tg,
                             int scale, int n, float* __restrict__ outp) {
  const int strd = 8 << scale;       // 8,16,32
  const int W = 80 >> scale;         // 80,40,20
  const int HW = W * W;
  __shared__ int s_key[64];
  __shared__ int s_val[64];
  int t = threadIdx.x;
  float boxterm = 0.f, objc = 0.f, clsc = 0.f, npos = 0.f;
  float bw = 0.f, bh = 0.f, dx = 0.f, dy = 0.f, clsf = 0.f;
  int gx = 0, gy = 0, best = 0;
  bool valid = false;
  if (t < 64) {
    if (t < NT) {
      const float* g = tg + ((size_t)n * NT + t) * 6;
      float x1 = g[0], y1 = g[1], x2 = g[2], y2 = g[3];
      clsf = g[5];
      valid = (x2 > x1) && (y2 > y1);
      float cx = (x1 + x2) * 0.5f, cy = (y1 + y2) * 0.5f;
      bw = x2 - x1; bh = y2 - y1;
      float fs = (float)strd;
      float gxf = cx / fs, gyf = cy / fs;
      float wm1 = (float)(W - 1);
      gx = (int)fminf(fmaxf(gxf, 0.f), wm1);   // clip then trunc, like astype
      gy = (int)fminf(fmaxf(gyf, 0.f), wm1);
      dx = gxf - (float)gx;                     // uses UNclipped gxf (ref)
      dy = gyf - (float)gy;
      float bi = -1e30f;
      for (int a = 0; a < 3; a++) {
        float aw = c_anch[scale][a][0], ah = c_anch[scale][a][1];
        float rw = bw / aw, rh = bh / ah;
        float il = fminf(rw, 1.f / (rw + 1e-6f)) * fminf(rh, 1.f / (rh + 1e-6f));
        if (il > bi) { bi = il; best = a; }     // strict > : first max (argmax)
      }
      s_key[t] = (best * W + gy) * W + gx;
      s_val[t] = valid ? 1 : 0;
    } else {
      s_key[t] = -1; s_val[t] = 0;
    }
  }
  __syncthreads();
  if (t < NT && valid) {
    // last valid target with same (anchor,gy,gx) wins (scan overwrite)
    bool win = true;
    int key = s_key[t];
    for (int u = t + 1; u < NT; ++u)
      if (s_val[u] && s_key[u] == key) { win = false; break; }
    if (win) {
      float aw = c_anch[scale][best][0], ah = c_anch[scale][best][1];
      const float* base = pred + (size_t)(n * 75 + best * 25) * HW + gy * W + gx;
      float tx = base[0];
      float ty = base[HW];
      float tw = base[2 * HW];
      float th = base[3 * HW];
      float ob = base[4 * HW];
      int clsi = (int)clsf;                     // trunc toward zero = astype
      bool clsok = (clsi >= 0) && (clsi < NC);
      int clscl = clsi < 0 ? 0 : (clsi > NC - 1 ? NC - 1 : clsi);
      float cv = base[(5 + clscl) * HW];
      float fs = (float)strd;
      float px = (2.f * sigm(tx) - 0.5f + (float)gx) * fs;
      float py = (2.f * sigm(ty) - 0.5f + (float)gy) * fs;
      float sw = 2.f * sigm(tw); float pw = sw * sw * aw * fs;
      float sh = 2.f * sigm(th); float ph = sh * sh * ah * fs;
      // target box (t_wh deliberately has NO stride factor, per reference)
      float qx = ((dx + 0.5f) + (float)gx) * fs;
      float qy = ((dy + 0.5f) + (float)gy) * fs;
      float rw = bw / aw; float qw = rw * rw * aw;
      float rh = bh / ah; float qh = rh * rh * ah;
      float b1x1 = px - pw * 0.5f, b1x2 = px + pw * 0.5f;
      float b1y1 = py - ph * 0.5f, b1y2 = py + ph * 0.5f;
      float b2x1 = qx - qw * 0.5f, b2x2 = qx + qw * 0.5f;
      float b2y1 = qy - qh * 0.5f, b2y2 = qy + qh * 0.5f;
      float iw = fmaxf(fminf(b1x2, b2x2) - fmaxf(b1x1, b2x1), 0.f);
      float ih = fmaxf(fminf(b1y2, b2y2) - fmaxf(b1y1, b2y1), 0.f);
      float inter = iw * ih;
      float uni = (b1x2 - b1x1) * (b1y2 - b1y1)
                + (b2x2 - b2x1) * (b2y2 - b2y1) - inter + 1e-7f;
      float iou = inter / uni;
      boxterm = 1.f - iou;
      objc = -ob;                    // bce(x,1)-bce(x,0) = -x
      clsc = clsok ? -cv : 0.f;
      npos = 1.f;
    }
  }
  if (t < 64) {
#pragma unroll
    for (int o = 32; o > 0; o >>= 1) {
      boxterm += __shfl_down(boxterm, o, 64);
      objc    += __shfl_down(objc, o, 64);
      clsc    += __shfl_down(clsc, o, 64);
      npos    += __shfl_down(npos, o, 64);
    }
    if (t == 0) {
      store2_rlx(outp, boxterm, objc);
      store2_rlx(outp + 2, clsc, npos);
    }
  }
}

// ---- finalizer: poll all 2016 flags, then reduce (R8 finalize body) ----
__device__ __forceinline__ int slot_scale(int d) {
  return d < 96 ? 0 : (d < 192 ? 1 : (d < DM ? 2 : (d < DM + DP0 ? 0 : 1)));
}

__device__ void finalize(const float* __restrict__ ws, float* __restrict__ out,
                         const unsigned int* __restrict__ flags) {
  int t = threadIdx.x;
  __shared__ int s_w[4];
  __shared__ int s_go;
  // ---- poll: exit only when ALL producer flags of THIS launch are set ----
  while (true) {
    bool ok = true;
#pragma unroll
    for (int r = 0; r < 8; ++r) {
      int idx = t + 256 * r;
      if (idx < PRODB)
        ok &= (__hip_atomic_load(&flags[idx], __ATOMIC_RELAXED, SCOPE_AGENT) != 0u);
    }
    unsigned long long ball = __ballot(ok);
    if ((t & 63) == 0) s_w[t >> 6] = (ball == ~0ull) ? 1 : 0;
    __syncthreads();
    if (t == 0) s_go = s_w[0] & s_w[1] & s_w[2] & s_w[3];
    __syncthreads();
    if (s_go) break;
  }
  __builtin_amdgcn_sched_barrier(0);   // keep partial loads after the poll
  // ---- reduce ----
  float2 dv[8];
#pragma unroll
  for (int r = 0; r < 7; ++r)
    dv[r] = load2_rlx(ws + WS_DENSE + 2 * (size_t)(t + 256 * r));
  bool has7 = t < DENSB - 1792;   // 128
  dv[7] = make_float2(0.f, 0.f);
  if (has7) dv[7] = load2_rlx(ws + WS_DENSE + 2 * (size_t)(t + 1792));
  float2 ta = make_float2(0.f, 0.f), tb = make_float2(0.f, 0.f);
  if (t < TGTB) {
    ta = load2_rlx(ws + 4 * (size_t)t);
    tb = load2_rlx(ws + 4 * (size_t)t + 2);
  }
  float acc[18];
#pragma unroll
  for (int k = 0; k < 18; k++) acc[k] = 0.f;
#pragma unroll
  for (int r = 0; r < 8; ++r) {
    int s = slot_scale(t + 256 * r);
    acc[2 * s] += dv[r].x;
    acc[2 * s + 1] += dv[r].y;
  }
  if (t < TGTB) {
    int s = t / NB;
    acc[6 + 4 * s + 0] += ta.x;
    acc[6 + 4 * s + 1] += ta.y;
    acc[6 + 4 * s + 2] += tb.x;
    acc[6 + 4 * s + 3] += tb.y;
  }
#pragma unroll
  for (int o = 32; o > 0; o >>= 1)
#pragma unroll
    for (int k = 0; k < 18; k++) acc[k] += __shfl_down(acc[k], o, 64);
  __shared__ float red[4][18];
  int wid = t >> 6, lane = t & 63;
  if (lane == 0)
#pragma unroll
    for (int k = 0; k < 18; k++) red[wid][k] = acc[k];
  __syncthreads();
  if (t == 0) {
    float r[18];
#pragma unroll
    for (int k = 0; k < 18; k++)
      r[k] = red[0][k] + red[1][k] + red[2][k] + red[3][k];
    const float objDen[3] = {614400.f, 153600.f, 38400.f};  // N*A*H*W
    float total = 0.f, lb = 0.f, lo = 0.f, lc = 0.f;
    for (int s = 0; s < 3; s++) {
      float np = r[6 + 4 * s + 3];
      float lbs = r[6 + 4 * s + 0] / fmaxf(np, 1.f);
      float los = (r[2 * s] + r[6 + 4 * s + 1]) / objDen[s];
      float lcs = (np > 0.f)
                    ? (r[2 * s + 1] + r[6 + 4 * s + 2]) / (objDen[s] * (float)NC)
                    : 0.f;
      total += 0.05f * lbs + 1.0f * los + 0.5f * lcs;
      lb += lbs; lo += los; lc += lcs;
    }
    out[0] = total; out[1] = lb; out[2] = lo; out[3] = lc;
  }
}

__global__ __launch_bounds__(THREADS)
void yolo_main(const float* __restrict__ p0, const float* __restrict__ p1,
               const float* __restrict__ p2, const float* __restrict__ tg,
               float* __restrict__ ws, float* __restrict__ out) {
  int b = blockIdx.x;
  unsigned int* flags = (unsigned int*)(ws + WS_FLAGS);
  if (b == PRODB) {                     // the single finalizer block
    finalize(ws, out, flags);
    return;
  }
  if (b < TGTB) {                       // targets FIRST: overlap latency
    int scale = b / NB, n = b - scale * NB;
    const float* p = scale == 0 ? p0 : (scale == 1 ? p1 : p2);
    target_block(p, tg, scale, n, ws + 4 * (size_t)b);
  } else {
    int d = b - TGTB;
    float* outp = ws + WS_DENSE + 2 * (size_t)d;
    if (d < 96) {                       // scale0 mixed (sub==0)
      int g = d, n = g / 3, a = g - n * 3;
      sum_dense<6400, true, PB0>(p0 + (size_t)(n * 75 + a * 25 + 4) * 6400, 0, outp);
    } else if (d < 192) {               // scale1 mixed
      int g = d - 96, n = g / 3, a = g - n * 3;
      sum_dense<1600, true, PB12>(p1 + (size_t)(n * 75 + a * 25 + 4) * 1600, 0, outp);
    } else if (d < DM) {                // scale2 mixed
      int g = d - 192, n = g / 3, a = g - n * 3;
      sum_dense<400, true, PB12>(p2 + (size_t)(n * 75 + a * 25 + 4) * 400, 0, outp);
    } else if (d < DM + DP0) {          // scale0 pure-cls
      int q = d - DM;
      int g = q / 14, sub = 1 + (q - g * 14);
      int n = g / 3, a = g - n * 3;
      sum_dense<6400, false, PB0>(p0 + (size_t)(n * 75 + a * 25 + 4) * 6400, sub, outp);
    } else {                            // scale1 pure-cls
      int q = d - (DM + DP0);
      int g = q / 3, sub = 1 + (q - g * 3);
      int n = g / 3, a = g - n * 3;
      sum_dense<1600, false, PB12>(p1 + (size_t)(n * 75 + a * 25 + 4) * 1600, sub, outp);
    }
  }
  // publish: own-flag store AFTER this thread's partial stores are ACKed.
  // Distinct address per block, plain atomic store — NO RMW (R4/R6 lesson).
  if (threadIdx.x == 0) {
    asm volatile("s_waitcnt vmcnt(0)" ::: "memory");
    __hip_atomic_store(&flags[b], 1u, __ATOMIC_RELAXED, SCOPE_AGENT);
  }
}

extern "C" void kernel_launch(void* const* d_in, const int* in_sizes, int n_in,
                              void* d_out, int out_size, void* d_ws, size_t ws_size,
                              hipStream_t stream) {
  const float* p0 = (const float*)d_in[0];
  const float* p1 = (const float*)d_in[1];
  const float* p2 = (const float*)d_in[2];
  const float* tg = (const float*)d_in[3];
  float* ws = (float*)d_ws;
  // zero the 2016 flags each launch (8064B fill node; graph-capturable)
  hipMemsetAsync(ws + WS_FLAGS, 0, PRODB * sizeof(unsigned int), stream);
  yolo_main<<<PRODB + 1, THREADS, 0, stream>>>(p0, p1, p2, tg, ws, (float*)d_out);
}

// Round 10
// 21.059 us; speedup vs baseline: 1.3159x; 1.3159x over previous
//
#include <hip/hip_runtime.h>

// YOLO loss, MI355X.
// R10 = R8 (best: 21.46us) + float4 partial loads in yolo_final.
// Fusion verdict (R4/R6/R9, permanent): on gfx950 ANY in-kernel cross-XCD
// consumer loses to a 2nd graph node: ordered RMW => per-XCD L2 wb/inv
// (~100us); relaxed same-address RMW => coherence-point serialization
// (~50us); per-block flags + poll => poll sweeps bypass caches and add a
// multi-us tail (+6us). Two-kernel structure is optimal here.

#define NB 32      // batch
#define NT 60      // targets per image
#define NC 20      // classes
#define THREADS 256

#define TGTB 96               // 3 scales * 32 batches, blocks 0..95
// dense: 96 groups/scale; blocks-per-group {15,4,1}; mixed first, then pure
#define DM  288               // mixed blocks: 96 per scale
#define DP0 1344              // scale0 pure: 96*14
#define DP1 288               // scale1 pure: 96*3
#define DENSB (DM + DP0 + DP1)   // 1920
#define PB0 2240              // f4/block scale0 (8*256 + 192)
#define PB12 2100             // f4/block scale1/2 (8*256 + 52)

// ws float layout: [0..383] tgt partials 96*4; [384..] dense 1920*2
#define WS_DENSE 384

__constant__ float c_anch[3][3][2] = {
  {{10.f/640.f, 13.f/640.f}, {16.f/640.f, 30.f/640.f}, {33.f/640.f, 23.f/640.f}},
  {{30.f/640.f, 61.f/640.f}, {62.f/640.f, 45.f/640.f}, {59.f/640.f, 119.f/640.f}},
  {{116.f/640.f, 90.f/640.f}, {156.f/640.f, 198.f/640.f}, {373.f/640.f, 326.f/640.f}},
};

__device__ __forceinline__ float sigm(float x) {
  return 1.f / (1.f + __expf(-x));
}
// one factor of the softplus product: 1 + exp(-|x|)
__device__ __forceinline__ float spf(float x) {
  return 1.f + __expf(-fabsf(x));
}
__device__ __forceinline__ float relu4(float4 v) {
  return (fmaxf(v.x, 0.f) + fmaxf(v.y, 0.f)) + (fmaxf(v.z, 0.f) + fmaxf(v.w, 0.f));
}
__device__ __forceinline__ float prod4(float4 v) {
  return (spf(v.x) * spf(v.y)) * (spf(v.z) * spf(v.w));
}

// ---- dense block. MIXED: sub==0 (contains the obj plane, boundary at
// OBJ4 = HW/4 f4); else pure-cls. Loads all issued before compute.
template<int HW, bool MIXED, int PB>
__device__ void sum_dense(const float* __restrict__ bp, int sub,
                          float* __restrict__ outp) {
  const int OBJ4 = HW / 4;          // f4 count of the obj plane
  const int FULLOBJ = OBJ4 >> 8;    // rounds fully inside obj: 6 / 1 / 0
  const int BLIM = OBJ4 & 255;      // boundary-round lane limit: 64/144/100
  int tid = threadIdx.x;
  int k0 = (MIXED ? 0 : sub * PB) + tid;
  float4 v[8];
#pragma unroll
  for (int u = 0; u < 8; ++u)
    v[u] = *reinterpret_cast<const float4*>(bp + 4 * (k0 + u * 256));
  const int TAIL = PB - 2048;                  // 192 or 52
  bool hasTail = tid < TAIL;
  float4 vt = make_float4(0.f, 0.f, 0.f, 0.f);
  if (hasTail) vt = *reinterpret_cast<const float4*>(bp + 4 * (k0 + 2048));

  float reluO = 0.f, prodO = 1.f;   // obj accumulators (unused in pure)
  float reluC = 0.f, prodC = 1.f;   // cls accumulators
#pragma unroll
  for (int u = 0; u < 8; ++u) {
    float r = relu4(v[u]);
    float pr = prod4(v[u]);
    if (MIXED && u < FULLOBJ) {            // compile-time: all obj
      reluO += r; prodO *= pr;
    } else if (MIXED && u == FULLOBJ) {    // the ONE per-lane round
      bool isO = tid < BLIM;
      reluO += isO ? r : 0.f;
      reluC += isO ? 0.f : r;
      prodO *= isO ? pr : 1.f;
      prodC *= isO ? 1.f : pr;
    } else {                                // compile-time: all cls
      reluC += r; prodC *= pr;
    }
  }
  {                                         // tail is always cls
    reluC += relu4(vt);                     // vt==0 when !hasTail -> +0
    prodC *= hasTail ? prod4(vt) : 1.f;
  }
  float accO = MIXED ? (reluO + __logf(prodO)) : 0.f;
  float accC = reluC + __logf(prodC);
#pragma unroll
  for (int o = 32; o > 0; o >>= 1) {
    if (MIXED) accO += __shfl_down(accO, o, 64);
    accC += __shfl_down(accC, o, 64);
  }
  __shared__ float sO[4], sC[4];
  int wid = threadIdx.x >> 6, lane = threadIdx.x & 63;
  if (lane == 0) { sO[wid] = accO; sC[wid] = accC; }
  __syncthreads();
  if (threadIdx.x == 0) {
    outp[0] = MIXED ? (sO[0] + sO[1] + sO[2] + sO[3]) : 0.f;
    outp[1] = sC[0] + sC[1] + sC[2] + sC[3];
  }
}

// ---- sparse target part: one block per (scale, n) ----
__device__ void target_block(const float* __restrict__ pred,
                             const float* __restrict__ tg,
                             int scale, int n, float* __restrict__ outp) {
  const int strd = 8 << scale;       // 8,16,32
  const int W = 80 >> scale;         // 80,40,20
  const int HW = W * W;
  __shared__ int s_key[64];
  __shared__ int s_val[64];
  int t = threadIdx.x;
  float boxterm = 0.f, objc = 0.f, clsc = 0.f, npos = 0.f;
  float bw = 0.f, bh = 0.f, dx = 0.f, dy = 0.f, clsf = 0.f;
  int gx = 0, gy = 0, best = 0;
  bool valid = false;
  if (t < 64) {
    if (t < NT) {
      const float* g = tg + ((size_t)n * NT + t) * 6;
      float x1 = g[0], y1 = g[1], x2 = g[2], y2 = g[3];
      clsf = g[5];
      valid = (x2 > x1) && (y2 > y1);
      float cx = (x1 + x2) * 0.5f, cy = (y1 + y2) * 0.5f;
      bw = x2 - x1; bh = y2 - y1;
      float fs = (float)strd;
      float gxf = cx / fs, gyf = cy / fs;
      float wm1 = (float)(W - 1);
      gx = (int)fminf(fmaxf(gxf, 0.f), wm1);   // clip then trunc, like astype
      gy = (int)fminf(fmaxf(gyf, 0.f), wm1);
      dx = gxf - (float)gx;                     // uses UNclipped gxf (ref)
      dy = gyf - (float)gy;
      float bi = -1e30f;
      for (int a = 0; a < 3; a++) {
        float aw = c_anch[scale][a][0], ah = c_anch[scale][a][1];
        float rw = bw / aw, rh = bh / ah;
        float il = fminf(rw, 1.f / (rw + 1e-6f)) * fminf(rh, 1.f / (rh + 1e-6f));
        if (il > bi) { bi = il; best = a; }     // strict > : first max (argmax)
      }
      s_key[t] = (best * W + gy) * W + gx;
      s_val[t] = valid ? 1 : 0;
    } else {
      s_key[t] = -1; s_val[t] = 0;
    }
  }
  __syncthreads();
  if (t < NT && valid) {
    // last valid target with same (anchor,gy,gx) wins (scan overwrite)
    bool win = true;
    int key = s_key[t];
    for (int u = t + 1; u < NT; ++u)
      if (s_val[u] && s_key[u] == key) { win = false; break; }
    if (win) {
      float aw = c_anch[scale][best][0], ah = c_anch[scale][best][1];
      const float* base = pred + (size_t)(n * 75 + best * 25) * HW + gy * W + gx;
      float tx = base[0];
      float ty = base[HW];
      float tw = base[2 * HW];
      float th = base[3 * HW];
      float ob = base[4 * HW];
      int clsi = (int)clsf;                     // trunc toward zero = astype
      bool clsok = (clsi >= 0) && (clsi < NC);
      int clscl = clsi < 0 ? 0 : (clsi > NC - 1 ? NC - 1 : clsi);
      float cv = base[(5 + clscl) * HW];
      float fs = (float)strd;
      float px = (2.f * sigm(tx) - 0.5f + (float)gx) * fs;
      float py = (2.f * sigm(ty) - 0.5f + (float)gy) * fs;
      float sw = 2.f * sigm(tw); float pw = sw * sw * aw * fs;
      float sh = 2.f * sigm(th); float ph = sh * sh * ah * fs;
      // target box (t_wh deliberately has NO stride factor, per reference)
      float qx = ((dx + 0.5f) + (float)gx) * fs;
      float qy = ((dy + 0.5f) + (float)gy) * fs;
      float rw = bw / aw; float qw = rw * rw * aw;
      float rh = bh / ah; float qh = rh * rh * ah;
      float b1x1 = px - pw * 0.5f, b1x2 = px + pw * 0.5f;
      float b1y1 = py - ph * 0.5f, b1y2 = py + ph * 0.5f;
      float b2x1 = qx - qw * 0.5f, b2x2 = qx + qw * 0.5f;
      float b2y1 = qy - qh * 0.5f, b2y2 = qy + qh * 0.5f;
      float iw = fmaxf(fminf(b1x2, b2x2) - fmaxf(b1x1, b2x1), 0.f);
      float ih = fmaxf(fminf(b1y2, b2y2) - fmaxf(b1y1, b2y1), 0.f);
      float inter = iw * ih;
      float uni = (b1x2 - b1x1) * (b1y2 - b1y1)
                + (b2x2 - b2x1) * (b2y2 - b2y1) - inter + 1e-7f;
      float iou = inter / uni;
      boxterm = 1.f - iou;
      objc = -ob;                    // bce(x,1)-bce(x,0) = -x
      clsc = clsok ? -cv : 0.f;
      npos = 1.f;
    }
  }
  if (t < 64) {
#pragma unroll
    for (int o = 32; o > 0; o >>= 1) {
      boxterm += __shfl_down(boxterm, o, 64);
      objc    += __shfl_down(objc, o, 64);
      clsc    += __shfl_down(clsc, o, 64);
      npos    += __shfl_down(npos, o, 64);
    }
    if (t == 0) {
      outp[0] = boxterm; outp[1] = objc; outp[2] = clsc; outp[3] = npos;
    }
  }
}

__global__ __launch_bounds__(THREADS)
void yolo_main(const float* __restrict__ p0, const float* __restrict__ p1,
               const float* __restrict__ p2, const float* __restrict__ tg,
               float* __restrict__ ws) {
  int b = blockIdx.x;
  if (b < TGTB) {                       // targets FIRST: overlap latency
    int scale = b / NB, n = b - scale * NB;
    const float* p = scale == 0 ? p0 : (scale == 1 ? p1 : p2);
    target_block(p, tg, scale, n, ws + 4 * (size_t)b);
    return;
  }
  int d = b - TGTB;
  float* outp = ws + WS_DENSE + 2 * (size_t)d;
  // group g -> (n,a); base of contiguous 21-plane (obj+cls) chunk
  if (d < 96) {                         // scale0 mixed (sub==0)
    int g = d, n = g / 3, a = g - n * 3;
    sum_dense<6400, true, PB0>(p0 + (size_t)(n * 75 + a * 25 + 4) * 6400, 0, outp);
  } else if (d < 192) {                 // scale1 mixed
    int g = d - 96, n = g / 3, a = g - n * 3;
    sum_dense<1600, true, PB12>(p1 + (size_t)(n * 75 + a * 25 + 4) * 1600, 0, outp);
  } else if (d < DM) {                  // scale2 mixed (only blocks of scale2)
    int g = d - 192, n = g / 3, a = g - n * 3;
    sum_dense<400, true, PB12>(p2 + (size_t)(n * 75 + a * 25 + 4) * 400, 0, outp);
  } else if (d < DM + DP0) {            // scale0 pure-cls
    int q = d - DM;
    int g = q / 14, sub = 1 + (q - g * 14);
    int n = g / 3, a = g - n * 3;
    sum_dense<6400, false, PB0>(p0 + (size_t)(n * 75 + a * 25 + 4) * 6400, sub, outp);
  } else {                              // scale1 pure-cls
    int q = d - (DM + DP0);
    int g = q / 3, sub = 1 + (q - g * 3);
    int n = g / 3, a = g - n * 3;
    sum_dense<1600, false, PB12>(p1 + (size_t)(n * 75 + a * 25 + 4) * 1600, sub, outp);
  }
}

// ---- parallel finalize ----
// dense slot d -> scale: [0,96)=0,[96,192)=1,[192,288)=2,[288,1632)=0,rest=1
// All region boundaries are EVEN -> a float4 (slot pair 2i,2i+1) never
// straddles a boundary -> one slot_scale lookup per float4.
__device__ __forceinline__ int slot_scale(int d) {
  return d < 96 ? 0 : (d < 192 ? 1 : (d < DM ? 2 : (d < DM + DP0 ? 0 : 1)));
}
__global__ __launch_bounds__(THREADS)
void yolo_final(const float* __restrict__ ws, float* __restrict__ out) {
  int t = threadIdx.x;
  // dense partials as float4: 960 f4 = 3 full rounds + 192-lane round
  float4 dv[4];
#pragma unroll
  for (int r = 0; r < 3; ++r)
    dv[r] = *reinterpret_cast<const float4*>(ws + WS_DENSE + 4 * (size_t)(t + 256 * r));
  bool has3 = t < 192;                  // 960 - 768
  dv[3] = make_float4(0.f, 0.f, 0.f, 0.f);
  if (has3)
    dv[3] = *reinterpret_cast<const float4*>(ws + WS_DENSE + 4 * (size_t)(t + 768));
  float4 tv = make_float4(0.f, 0.f, 0.f, 0.f);
  if (t < TGTB)
    tv = *reinterpret_cast<const float4*>(ws + 4 * (size_t)t);

  float acc[18];
#pragma unroll
  for (int k = 0; k < 18; k++) acc[k] = 0.f;
#pragma unroll
  for (int r = 0; r < 4; ++r) {
    int s = slot_scale(2 * (t + 256 * r));
    acc[2 * s] += dv[r].x + dv[r].z;
    acc[2 * s + 1] += dv[r].y + dv[r].w;
  }
  if (t < TGTB) {
    int s = t / NB;
    acc[6 + 4 * s + 0] += tv.x;
    acc[6 + 4 * s + 1] += tv.y;
    acc[6 + 4 * s + 2] += tv.z;
    acc[6 + 4 * s + 3] += tv.w;
  }
#pragma unroll
  for (int o = 32; o > 0; o >>= 1)
#pragma unroll
    for (int k = 0; k < 18; k++) acc[k] += __shfl_down(acc[k], o, 64);
  __shared__ float red[4][18];
  int wid = t >> 6, lane = t & 63;
  if (lane == 0)
#pragma unroll
    for (int k = 0; k < 18; k++) red[wid][k] = acc[k];
  __syncthreads();
  if (t == 0) {
    float r[18];
#pragma unroll
    for (int k = 0; k < 18; k++)
      r[k] = red[0][k] + red[1][k] + red[2][k] + red[3][k];
    const float objDen[3] = {614400.f, 153600.f, 38400.f};  // N*A*H*W
    float total = 0.f, lb = 0.f, lo = 0.f, lc = 0.f;
    for (int s = 0; s < 3; s++) {
      float np = r[6 + 4 * s + 3];
      float lbs = r[6 + 4 * s + 0] / fmaxf(np, 1.f);
      float los = (r[2 * s] + r[6 + 4 * s + 1]) / objDen[s];
      float lcs = (np > 0.f)
                    ? (r[2 * s + 1] + r[6 + 4 * s + 2]) / (objDen[s] * (float)NC)
                    : 0.f;
      total += 0.05f * lbs + 1.0f * los + 0.5f * lcs;
      lb += lbs; lo += los; lc += lcs;
    }
    out[0] = total; out[1] = lb; out[2] = lo; out[3] = lc;
  }
}

extern "C" void kernel_launch(void* const* d_in, const int* in_sizes, int n_in,
                              void* d_out, int out_size, void* d_ws, size_t ws_size,
                              hipStream_t stream) {
  const float* p0 = (const float*)d_in[0];
  const float* p1 = (const float*)d_in[1];
  const float* p2 = (const float*)d_in[2];
  const float* tg = (const float*)d_in[3];
  float* ws = (float*)d_ws;
  // every ws slot used is written each launch -> no memset needed; fully
  // deterministic (no float atomics, fixed reduction orders).
  yolo_main<<<TGTB + DENSB, THREADS, 0, stream>>>(p0, p1, p2, tg, ws);
  yolo_final<<<1, THREADS, 0, stream>>>(ws, (float*)d_out);
}